// Round 1
// baseline (17371.333 us; speedup 1.0000x reference)
//
#include <hip/hip_runtime.h>
#include <hip/hip_cooperative_groups.h>

typedef unsigned short u16;
typedef __attribute__((ext_vector_type(8))) short short8;
typedef __attribute__((ext_vector_type(4))) float f32x4;

#define T_STEPS 512
#define HF_OFF 50331648UL

__device__ __forceinline__ u16 f2bf(float f) {
  union { float f; unsigned u; } v; v.f = f;
  unsigned r = (v.u + 0x7FFFu + ((v.u >> 16) & 1u)) >> 16;
  return (u16)r;
}

__device__ __forceinline__ short8 pack8(float4 f0, float4 f1) {
  short8 v;
  v[0]=(short)f2bf(f0.x); v[1]=(short)f2bf(f0.y); v[2]=(short)f2bf(f0.z); v[3]=(short)f2bf(f0.w);
  v[4]=(short)f2bf(f1.x); v[5]=(short)f2bf(f1.y); v[6]=(short)f2bf(f1.z); v[7]=(short)f2bf(f1.w);
  return v;
}

__device__ __forceinline__ float sigm(float x) { return 1.0f / (1.0f + __expf(-x)); }
__device__ __forceinline__ float tanh_f(float x) { return 1.0f - 2.0f / (__expf(2.0f * x) + 1.0f); }

// Build Wr[l][j*4+g][k] (bf16, K-major, k<768 from W_ih, k>=768 from W_hh),
// rows permuted so gate cols for h-column j are contiguous (i,f,g,o interleave).
__global__ void prep_weights(const float* __restrict__ Wih, const float* __restrict__ Whh,
                             u16* __restrict__ Wr) {
  int idx = blockIdx.x * blockDim.x + threadIdx.x;
  if (idx >= 2 * 3072 * 192) return;
  int r = idx / 192;
  int kc = (idx - r * 192) * 8;
  int l = r / 3072;
  int rr = r - l * 3072;
  int j = rr >> 2, g = rr & 3;
  int srow = l * 3072 + g * 768 + j;
  const float* src = (kc < 768) ? (Wih + (size_t)srow * 768 + kc)
                                : (Whh + (size_t)srow * 768 + (kc - 768));
  float4 f0 = *(const float4*)src;
  float4 f1 = *(const float4*)(src + 4);
  *(short8*)(Wr + (size_t)r * 1536 + kc) = pack8(f0, f1);
}

// bcat[l][j*4+g] = b_ih + b_hh (same permutation); hbuf[l][1] = bf16(h0[l]).
__global__ void prep_misc(const float* __restrict__ h0, const float* __restrict__ bih,
                          const float* __restrict__ bhh, u16* __restrict__ hbuf,
                          float* __restrict__ bcat) {
  int idx = blockIdx.x * blockDim.x + threadIdx.x;
  if (idx < 6144) {
    int l = idx / 3072;
    int rr = idx - l * 3072;
    int j = rr >> 2, g = rr & 3;
    int s = l * 3072 + g * 768 + j;
    bcat[idx] = bih[s] + bhh[s];
  }
  int hi = idx - 6144;
  if (hi >= 0 && hi < 98304) {
    int l = hi / 49152;
    int bj = hi - l * 49152;
    hbuf[(size_t)(l * 2 + 1) * 49152 + bj] = f2bf(h0[hi]);
  }
}

// Persistent kernel: 128 WGs (wg>>6 = layer, wg&63 = wgi owning h-cols [wgi*12, +12)).
// Wavefront s: layer0 does t=s, layer1 does t=s-1; one grid.sync per wavefront.
__global__ void __launch_bounds__(256, 2)
lstm_persistent(const float* __restrict__ x, const float* __restrict__ h0,
                const float* __restrict__ c0, const int* __restrict__ len,
                const u16* __restrict__ Wr, const float* __restrict__ bcat,
                u16* __restrict__ hbuf, float* __restrict__ out) {
  __shared__ u16 lA[64 * 256];   // A chunk  [64][256] bf16, swizzled
  __shared__ u16 lW[48 * 256];   // W chunk  [48][256] bf16, swizzled
  __shared__ float lG[4][16 * 48]; // per-wave gate staging
  __shared__ float lBias[48];
  __shared__ int lLen[64];

  const int tid = threadIdx.x;
  const int wv = tid >> 6;
  const int ln = tid & 63;
  const int wg = blockIdx.x;
  const int layer = wg >> 6;
  const int wgi = wg & 63;
  const int n0 = wgi * 48;   // gate-col base (permuted rows of Wr)
  const int j0 = wgi * 12;   // h-col base

  if (tid < 48) lBias[tid] = bcat[layer * 3072 + n0 + tid];
  if (tid < 64) lLen[tid] = len[tid];

  // Each thread owns 3 (b, j) state cells: p = ln*3+e -> (bl = p/12, jj = p%12)
  int bl[3], jj[3];
  float cReg[3], hKeep[3];
#pragma unroll
  for (int e = 0; e < 3; ++e) {
    int p = ln * 3 + e;
    bl[e] = p / 12;
    jj[e] = p % 12;
    int b = wv * 16 + bl[e];
    int j = j0 + jj[e];
    cReg[e] = c0[(size_t)(layer * 64 + b) * 768 + j];
    hKeep[e] = h0[(size_t)(layer * 64 + b) * 768 + j];
  }
  __syncthreads();

  cooperative_groups::grid_group grid = cooperative_groups::this_grid();

  for (int s = 0; s <= T_STEPS; ++s) {
    const int t = (layer == 0) ? s : s - 1;
    if (t >= 0 && t < T_STEPS) {
      const u16* hprev = hbuf + (size_t)(layer * 2 + ((t - 1) & 1)) * 49152;
      const u16* h0cur = hbuf + (size_t)(t & 1) * 49152;  // layer1 low-K source
      u16* hout = hbuf + (size_t)(layer * 2 + (t & 1)) * 49152;

      f32x4 acc[3] = {};

      for (int ck = 0; ck < 6; ++ck) {
        const int koff = ck * 256;
        // ---- stage A [64][256] ----
        if (layer == 0 && ck < 3) {
          const float* src = x + (size_t)t * 49152 + koff;
#pragma unroll
          for (int it = tid; it < 2048; it += 256) {
            int row = it >> 5;
            int kk = (it & 31) << 3;
            const float* p = src + row * 768 + kk;
            float4 f0 = *(const float4*)p;
            float4 f1 = *(const float4*)(p + 4);
            *(short8*)&lA[row * 256 + (kk ^ ((row & 7) << 3))] = pack8(f0, f1);
          }
        } else {
          const u16* src = (ck < 3) ? (h0cur + koff) : (hprev + (koff - 768));
#pragma unroll
          for (int it = tid; it < 2048; it += 256) {
            int row = it >> 5;
            int kk = (it & 31) << 3;
            short8 v = *(const short8*)(src + row * 768 + kk);
            *(short8*)&lA[row * 256 + (kk ^ ((row & 7) << 3))] = v;
          }
        }
        // ---- stage W [48][256] ----
        {
          const u16* srcW = Wr + (size_t)(layer * 3072 + n0) * 1536 + koff;
#pragma unroll
          for (int it = tid; it < 1536; it += 256) {
            int row = it >> 5;
            int kk = (it & 31) << 3;
            short8 v = *(const short8*)(srcW + (size_t)row * 1536 + kk);
            *(short8*)&lW[row * 256 + (kk ^ ((row & 7) << 3))] = v;
          }
        }
        __syncthreads();

        // ---- MFMA: wave wv owns rows [16wv,16wv+16), all 48 cols ----
        const int arow = wv * 16 + (ln & 15);
        const int kb = (ln >> 4) << 3;
        const int aswz = (arow & 7) << 3;
#pragma unroll
        for (int kk = 0; kk < 8; ++kk) {
          const int k = kk * 32 + kb;
          short8 a = *(const short8*)&lA[arow * 256 + (k ^ aswz)];
#pragma unroll
          for (int ct = 0; ct < 3; ++ct) {
            const int nrow = ct * 16 + (ln & 15);
            short8 b = *(const short8*)&lW[nrow * 256 + (k ^ ((nrow & 7) << 3))];
            acc[ct] = __builtin_amdgcn_mfma_f32_16x16x32_bf16(a, b, acc[ct], 0, 0, 0);
          }
        }
        __syncthreads();
      }

      // ---- gates -> LDS (per-wave region), C layout: col=lane&15, row=(lane>>4)*4+r ----
      {
        const int c0l = ln & 15;
        const int r0 = (ln >> 4) << 2;
#pragma unroll
        for (int ct = 0; ct < 3; ++ct)
#pragma unroll
          for (int r = 0; r < 4; ++r)
            lG[wv][(r0 + r) * 48 + ct * 16 + c0l] = acc[ct][r];
      }
      __syncthreads();

      // ---- pointwise LSTM cell + mask ----
#pragma unroll
      for (int e = 0; e < 3; ++e) {
        const int b = wv * 16 + bl[e];
        const int jloc = jj[e];
        const float4 g4 = *(const float4*)&lG[wv][bl[e] * 48 + jloc * 4];
        const float4 bb = *(const float4*)&lBias[jloc * 4];
        float gi = g4.x + bb.x;
        float gf = g4.y + bb.y;
        float gg = g4.z + bb.z;
        float go = g4.w + bb.w;
        float cn = sigm(gf) * cReg[e] + sigm(gi) * tanh_f(gg);
        float hn = sigm(go) * tanh_f(cn);
        const bool act = t < lLen[b];
        const float hm = act ? hn : hKeep[e];
        const float cm = act ? cn : cReg[e];
        hKeep[e] = hm;
        cReg[e] = cm;
        const int j = j0 + jloc;
        out[((size_t)(t * 64 + b) * 2 + layer) * 768 + j] = hm;
        hout[b * 768 + j] = f2bf(hm);
      }
      __syncthreads();
    }
    grid.sync();
  }

  // final states
  float* hf = out + HF_OFF;
  float* cf = out + HF_OFF + 98304;
#pragma unroll
  for (int e = 0; e < 3; ++e) {
    const int b = wv * 16 + bl[e];
    const int j = j0 + jj[e];
    hf[(size_t)(layer * 64 + b) * 768 + j] = hKeep[e];
    cf[(size_t)(layer * 64 + b) * 768 + j] = cReg[e];
  }
}

extern "C" void kernel_launch(void* const* d_in, const int* in_sizes, int n_in,
                              void* d_out, int out_size, void* d_ws, size_t ws_size,
                              hipStream_t stream) {
  const float* x   = (const float*)d_in[0];
  const float* h0  = (const float*)d_in[1];
  const float* c0  = (const float*)d_in[2];
  const float* Wih = (const float*)d_in[3];
  const float* Whh = (const float*)d_in[4];
  const float* bih = (const float*)d_in[5];
  const float* bhh = (const float*)d_in[6];
  const int*   len = (const int*)d_in[7];
  float* out = (float*)d_out;

  u16*   Wr   = (u16*)d_ws;                            // 2*3072*1536 bf16 = 18.87 MB
  float* bcat = (float*)((char*)d_ws + 18874368);      // 6144 f32
  u16*   hbuf = (u16*)((char*)d_ws + 18898944);        // 2 layers * 2 bufs * 64*768 bf16

  {
    const int units = 2 * 3072 * 192;
    prep_weights<<<(units + 255) / 256, 256, 0, stream>>>(Wih, Whh, Wr);
    const int n2 = 6144 + 98304;
    prep_misc<<<(n2 + 255) / 256, 256, 0, stream>>>(h0, bih, bhh, hbuf, bcat);
  }

  void* args[] = { (void*)&x, (void*)&h0, (void*)&c0, (void*)&len,
                   (void*)&Wr, (void*)&bcat, (void*)&hbuf, (void*)&out };
  hipLaunchCooperativeKernel((const void*)lstm_persistent, dim3(128), dim3(256),
                             args, 0, stream);
}

// Round 2
// 13693.843 us; speedup vs baseline: 1.2686x; 1.2686x over previous
//
#include <hip/hip_runtime.h>

typedef unsigned short u16;
typedef __attribute__((ext_vector_type(8))) short short8;
typedef __attribute__((ext_vector_type(4))) float f32x4;

#define T_STEPS 512
#define HF_OFF 50331648UL
#define NWG 128

__device__ __forceinline__ u16 f2bf(float f) {
  union { float f; unsigned u; } v; v.f = f;
  unsigned r = (v.u + 0x7FFFu + ((v.u >> 16) & 1u)) >> 16;
  return (u16)r;
}

__device__ __forceinline__ short8 pack8(float4 f0, float4 f1) {
  short8 v;
  v[0]=(short)f2bf(f0.x); v[1]=(short)f2bf(f0.y); v[2]=(short)f2bf(f0.z); v[3]=(short)f2bf(f0.w);
  v[4]=(short)f2bf(f1.x); v[5]=(short)f2bf(f1.y); v[6]=(short)f2bf(f1.z); v[7]=(short)f2bf(f1.w);
  return v;
}

__device__ __forceinline__ float sigm(float x) { return 1.0f / (1.0f + __expf(-x)); }
__device__ __forceinline__ float tanh_f(float x) { return 1.0f - 2.0f / (__expf(2.0f * x) + 1.0f); }

// Build Wr[l][j*4+g][k] (bf16, K-major, k<768 from W_ih, k>=768 from W_hh),
// rows permuted so gate cols for h-column j are contiguous (i,f,g,o interleave).
__global__ void prep_weights(const float* __restrict__ Wih, const float* __restrict__ Whh,
                             u16* __restrict__ Wr) {
  int idx = blockIdx.x * blockDim.x + threadIdx.x;
  if (idx >= 2 * 3072 * 192) return;
  int r = idx / 192;
  int kc = (idx - r * 192) * 8;
  int l = r / 3072;
  int rr = r - l * 3072;
  int j = rr >> 2, g = rr & 3;
  int srow = l * 3072 + g * 768 + j;
  const float* src = (kc < 768) ? (Wih + (size_t)srow * 768 + kc)
                                : (Whh + (size_t)srow * 768 + (kc - 768));
  float4 f0 = *(const float4*)src;
  float4 f1 = *(const float4*)(src + 4);
  *(short8*)(Wr + (size_t)r * 1536 + kc) = pack8(f0, f1);
}

// bcat[l][j*4+g] = b_ih + b_hh (same permutation); hbuf[l][1] = bf16(h0[l]);
// zero the barrier state.
__global__ void prep_misc(const float* __restrict__ h0, const float* __restrict__ bih,
                          const float* __restrict__ bhh, u16* __restrict__ hbuf,
                          float* __restrict__ bcat, int* __restrict__ bar) {
  int idx = blockIdx.x * blockDim.x + threadIdx.x;
  if (idx < 64) bar[idx] = 0;
  if (idx < 6144) {
    int l = idx / 3072;
    int rr = idx - l * 3072;
    int j = rr >> 2, g = rr & 3;
    int s = l * 3072 + g * 768 + j;
    bcat[idx] = bih[s] + bhh[s];
  }
  int hi = idx - 6144;
  if (hi >= 0 && hi < 98304) {
    int l = hi / 49152;
    int bj = hi - l * 49152;
    hbuf[(size_t)(l * 2 + 1) * 49152 + bj] = f2bf(h0[hi]);
  }
}

// Persistent kernel: 128 WGs (wg>>6 = layer, wg&63 = wgi owning h-cols [wgi*12, +12)).
// Wavefront s: layer0 does t=s, layer1 does t=s-1; one custom barrier per wavefront.
__global__ void __launch_bounds__(256, 2)
lstm_persistent(const float* __restrict__ x, const float* __restrict__ h0,
                const float* __restrict__ c0, const int* __restrict__ len,
                const u16* __restrict__ Wr, const float* __restrict__ bcat,
                u16* __restrict__ hbuf, float* __restrict__ out,
                int* __restrict__ bar) {
  __shared__ u16 lA[64 * 256];   // A chunk  [64][256] bf16, swizzled
  __shared__ u16 lW[48 * 256];   // W chunk  [48][256] bf16, swizzled
  __shared__ float lG[4][16 * 48]; // per-wave gate staging
  __shared__ float lBias[48];
  __shared__ int lLen[64];

  const int tid = threadIdx.x;
  const int wv = tid >> 6;
  const int ln = tid & 63;
  const int wg = blockIdx.x;
  const int layer = wg >> 6;
  const int wgi = wg & 63;
  const int n0 = wgi * 48;   // gate-col base (permuted rows of Wr)
  const int j0 = wgi * 12;   // h-col base

  int* bar_ctr  = bar;       // arrival counter
  int* bar_flag = bar + 32;  // phase flag (separate 128B line)

  if (tid < 48) lBias[tid] = bcat[layer * 3072 + n0 + tid];
  if (tid < 64) lLen[tid] = len[tid];

  // Each thread owns 3 (b, j) state cells: p = ln*3+e -> (bl = p/12, jj = p%12)
  int bl[3], jj[3];
  float cReg[3], hKeep[3];
#pragma unroll
  for (int e = 0; e < 3; ++e) {
    int p = ln * 3 + e;
    bl[e] = p / 12;
    jj[e] = p % 12;
    int b = wv * 16 + bl[e];
    int j = j0 + jj[e];
    cReg[e] = c0[(size_t)(layer * 64 + b) * 768 + j];
    hKeep[e] = h0[(size_t)(layer * 64 + b) * 768 + j];
  }
  __syncthreads();

  for (int s = 0; s <= T_STEPS; ++s) {
    const int t = (layer == 0) ? s : s - 1;
    if (t >= 0 && t < T_STEPS) {
      const u16* hprev = hbuf + (size_t)(layer * 2 + ((t - 1) & 1)) * 49152;
      const u16* h0cur = hbuf + (size_t)(t & 1) * 49152;  // layer1 low-K source
      u16* hout = hbuf + (size_t)(layer * 2 + (t & 1)) * 49152;

      f32x4 acc[3] = {};

      for (int ck = 0; ck < 6; ++ck) {
        const int koff = ck * 256;
        // ---- stage A [64][256] ----
        if (layer == 0 && ck < 3) {
          const float* src = x + (size_t)t * 49152 + koff;
#pragma unroll
          for (int it = tid; it < 2048; it += 256) {
            int row = it >> 5;
            int kk = (it & 31) << 3;
            const float* p = src + row * 768 + kk;
            float4 f0 = *(const float4*)p;
            float4 f1 = *(const float4*)(p + 4);
            *(short8*)&lA[row * 256 + (kk ^ ((row & 7) << 3))] = pack8(f0, f1);
          }
        } else {
          const u16* src = (ck < 3) ? (h0cur + koff) : (hprev + (koff - 768));
#pragma unroll
          for (int it = tid; it < 2048; it += 256) {
            int row = it >> 5;
            int kk = (it & 31) << 3;
            short8 v = *(const short8*)(src + row * 768 + kk);
            *(short8*)&lA[row * 256 + (kk ^ ((row & 7) << 3))] = v;
          }
        }
        // ---- stage W [48][256] ----
        {
          const u16* srcW = Wr + (size_t)(layer * 3072 + n0) * 1536 + koff;
#pragma unroll
          for (int it = tid; it < 1536; it += 256) {
            int row = it >> 5;
            int kk = (it & 31) << 3;
            short8 v = *(const short8*)(srcW + (size_t)row * 1536 + kk);
            *(short8*)&lW[row * 256 + (kk ^ ((row & 7) << 3))] = v;
          }
        }
        __syncthreads();

        // ---- MFMA: wave wv owns rows [16wv,16wv+16), all 48 cols ----
        const int arow = wv * 16 + (ln & 15);
        const int kb = (ln >> 4) << 3;
        const int aswz = (arow & 7) << 3;
#pragma unroll
        for (int kk = 0; kk < 8; ++kk) {
          const int k = kk * 32 + kb;
          short8 a = *(const short8*)&lA[arow * 256 + (k ^ aswz)];
#pragma unroll
          for (int ct = 0; ct < 3; ++ct) {
            const int nrow = ct * 16 + (ln & 15);
            short8 b = *(const short8*)&lW[nrow * 256 + (k ^ ((nrow & 7) << 3))];
            acc[ct] = __builtin_amdgcn_mfma_f32_16x16x32_bf16(a, b, acc[ct], 0, 0, 0);
          }
        }
        __syncthreads();
      }

      // ---- gates -> LDS (per-wave region; reader is the same wave) ----
      {
        const int c0l = ln & 15;
        const int r0 = (ln >> 4) << 2;
#pragma unroll
        for (int ct = 0; ct < 3; ++ct)
#pragma unroll
          for (int r = 0; r < 4; ++r)
            lG[wv][(r0 + r) * 48 + ct * 16 + c0l] = acc[ct][r];
      }

      // ---- pointwise LSTM cell + mask ----
#pragma unroll
      for (int e = 0; e < 3; ++e) {
        const int b = wv * 16 + bl[e];
        const int jloc = jj[e];
        const float4 g4 = *(const float4*)&lG[wv][bl[e] * 48 + jloc * 4];
        const float4 bb = *(const float4*)&lBias[jloc * 4];
        float gi = g4.x + bb.x;
        float gf = g4.y + bb.y;
        float gg = g4.z + bb.z;
        float go = g4.w + bb.w;
        float cn = sigm(gf) * cReg[e] + sigm(gi) * tanh_f(gg);
        float hn = sigm(go) * tanh_f(cn);
        const bool act = t < lLen[b];
        const float hm = act ? hn : hKeep[e];
        const float cm = act ? cn : cReg[e];
        hKeep[e] = hm;
        cReg[e] = cm;
        const int j = j0 + jloc;
        out[((size_t)(t * 64 + b) * 2 + layer) * 768 + j] = hm;
        hout[b * 768 + j] = f2bf(hm);
      }
    }

    // ---- custom device barrier (replaces grid.sync) ----
    __syncthreads();
    if (tid == 0) {
      __threadfence();  // release: flush this CU/XCD caches so h is visible
      int old = __hip_atomic_fetch_add(bar_ctr, 1, __ATOMIC_RELEASE,
                                       __HIP_MEMORY_SCOPE_AGENT);
      const int target = s + 1;
      if (old == NWG * (s + 1) - 1) {
        __hip_atomic_store(bar_flag, target, __ATOMIC_RELEASE,
                           __HIP_MEMORY_SCOPE_AGENT);
      } else {
        while (__hip_atomic_load(bar_flag, __ATOMIC_RELAXED,
                                 __HIP_MEMORY_SCOPE_AGENT) < target) {
          __builtin_amdgcn_s_sleep(1);
        }
      }
      __threadfence();  // acquire: invalidate so fresh h is read next step
    }
    __syncthreads();
  }

  // final states
  float* hf = out + HF_OFF;
  float* cf = out + HF_OFF + 98304;
#pragma unroll
  for (int e = 0; e < 3; ++e) {
    const int b = wv * 16 + bl[e];
    const int j = j0 + jj[e];
    hf[(size_t)(layer * 64 + b) * 768 + j] = hKeep[e];
    cf[(size_t)(layer * 64 + b) * 768 + j] = cReg[e];
  }
}

extern "C" void kernel_launch(void* const* d_in, const int* in_sizes, int n_in,
                              void* d_out, int out_size, void* d_ws, size_t ws_size,
                              hipStream_t stream) {
  const float* x   = (const float*)d_in[0];
  const float* h0  = (const float*)d_in[1];
  const float* c0  = (const float*)d_in[2];
  const float* Wih = (const float*)d_in[3];
  const float* Whh = (const float*)d_in[4];
  const float* bih = (const float*)d_in[5];
  const float* bhh = (const float*)d_in[6];
  const int*   len = (const int*)d_in[7];
  float* out = (float*)d_out;

  u16*   Wr   = (u16*)d_ws;                            // 2*3072*1536 bf16 = 18.87 MB
  float* bcat = (float*)((char*)d_ws + 18874368);      // 6144 f32
  u16*   hbuf = (u16*)((char*)d_ws + 18898944);        // 2 layers * 2 bufs * 64*768 bf16
  int*   bar  = (int*)((char*)d_ws + 19292160);        // barrier ctr + flag

  {
    const int units = 2 * 3072 * 192;
    prep_weights<<<(units + 255) / 256, 256, 0, stream>>>(Wih, Whh, Wr);
    const int n2 = 6144 + 98304;
    prep_misc<<<(n2 + 255) / 256, 256, 0, stream>>>(h0, bih, bhh, hbuf, bcat, bar);
  }

  void* args[] = { (void*)&x, (void*)&h0, (void*)&c0, (void*)&len,
                   (void*)&Wr, (void*)&bcat, (void*)&hbuf, (void*)&out,
                   (void*)&bar };
  hipLaunchCooperativeKernel((const void*)lstm_persistent, dim3(NWG), dim3(256),
                             args, 0, stream);
}